// Round 1
// baseline (3967.547 us; speedup 1.0000x reference)
//
#include <hip/hip_runtime.h>
#include <hip/hip_bf16.h>

#define B 128
#define T 64
#define E 512
#define H 512
#define A 512
#define V 10000
#define NPAD 10112   // 79*128

typedef __hip_bfloat16 bf16;
typedef __attribute__((ext_vector_type(8))) short bf16x8s;
typedef __attribute__((ext_vector_type(4))) float f32x4;

__device__ __forceinline__ bf16x8s ld8(const bf16* p) {
  return *reinterpret_cast<const bf16x8s*>(p);
}
__device__ __forceinline__ float sigm(float x) { return 1.f / (1.f + __expf(-x)); }

// One K=512 half of a 32x32 wave tile: C += X[m0:m0+32, :512] * W[n0:n0+32, :512]^T
// X rows are M, W rows are N (B^T form). MFMA 16x16x32 bf16.
__device__ __forceinline__ void mm512(const bf16* __restrict__ X, int ldx,
                                      const bf16* __restrict__ W, int ldw,
                                      int m0, int n0, int lane, f32x4 acc[2][2]) {
  const int r = lane & 15, ko = (lane >> 4) << 3;
  const bf16* xa = X + (size_t)(m0 + r) * ldx + ko;
  const bf16* wb = W + (size_t)(n0 + r) * ldw + ko;
  #pragma unroll 4
  for (int k = 0; k < 512; k += 32) {
    bf16x8s a0 = ld8(xa + k);
    bf16x8s a1 = ld8(xa + 16 * ldx + k);
    bf16x8s b0 = ld8(wb + k);
    bf16x8s b1 = ld8(wb + 16 * ldw + k);
    acc[0][0] = __builtin_amdgcn_mfma_f32_16x16x32_bf16(a0, b0, acc[0][0], 0, 0, 0);
    acc[0][1] = __builtin_amdgcn_mfma_f32_16x16x32_bf16(a0, b1, acc[0][1], 0, 0, 0);
    acc[1][0] = __builtin_amdgcn_mfma_f32_16x16x32_bf16(a1, b0, acc[1][0], 0, 0, 0);
    acc[1][1] = __builtin_amdgcn_mfma_f32_16x16x32_bf16(a1, b1, acc[1][1], 0, 0, 0);
  }
}

// ---------------- prep kernels ----------------

// xs_bf[t][b][e] = bf16( t==0 ? features[b][e] : emb_W[captions[b][t-1]][e] )
__global__ __launch_bounds__(256) void kxs(const float* __restrict__ feat,
                                           const int* __restrict__ cap,
                                           const float* __restrict__ embW,
                                           bf16* __restrict__ xs) {
  int idx = blockIdx.x * 256 + threadIdx.x;   // B*T*E/4 threads
  if (idx >= B * T * E / 4) return;
  int e4 = (idx & 127) << 2;
  int b = (idx >> 7) & 127;
  int t = idx >> 14;
  const float* src = (t == 0) ? (feat + (size_t)b * E)
                              : (embW + (size_t)cap[b * (T - 1) + (t - 1)] * E);
  float4 v = *reinterpret_cast<const float4*>(src + e4);
  bf16* d = xs + ((size_t)t * B + b) * E + e4;
  d[0] = __float2bfloat16(v.x); d[1] = __float2bfloat16(v.y);
  d[2] = __float2bfloat16(v.z); d[3] = __float2bfloat16(v.w);
}

__global__ __launch_bounds__(256) void kcast(const float* __restrict__ s,
                                             bf16* __restrict__ d, int n4) {
  int i = blockIdx.x * 256 + threadIdx.x;
  if (i >= n4) return;
  float4 v = *reinterpret_cast<const float4*>(s + (size_t)i * 4);
  d[i * 4 + 0] = __float2bfloat16(v.x); d[i * 4 + 1] = __float2bfloat16(v.y);
  d[i * 4 + 2] = __float2bfloat16(v.z); d[i * 4 + 3] = __float2bfloat16(v.w);
}

__global__ __launch_bounds__(256) void kpadW(const float* __restrict__ s,
                                             bf16* __restrict__ d) {
  int i = blockIdx.x * 256 + threadIdx.x;   // NPAD*H/4 threads
  if (i >= NPAD * H / 4) return;
  int row = (i << 2) / H;
  float4 v = make_float4(0.f, 0.f, 0.f, 0.f);
  if (row < V) v = *reinterpret_cast<const float4*>(s + (size_t)i * 4);
  d[i * 4 + 0] = __float2bfloat16(v.x); d[i * 4 + 1] = __float2bfloat16(v.y);
  d[i * 4 + 2] = __float2bfloat16(v.z); d[i * 4 + 3] = __float2bfloat16(v.w);
}

__global__ __launch_bounds__(256) void kbg(const float* __restrict__ bi,
                                           const float* __restrict__ bh,
                                           float* __restrict__ bg) {
  int i = blockIdx.x * 256 + threadIdx.x;
  if (i < 4 * H) bg[i] = bi[i] + bh[i];
}

// ---------------- per-step kernels ----------------

// scores = [x_t | h] @ att_W^T + att_b ; P' = exp(scores)*cnn (bf16) ; Z[b] += exp(scores)
__global__ __launch_bounds__(256) void kscore(const bf16* __restrict__ xt,
                                              const bf16* __restrict__ hb,
                                              const bf16* __restrict__ attW,
                                              const float* __restrict__ attb,
                                              const float* __restrict__ cnn,
                                              bf16* __restrict__ pbuf,
                                              float* __restrict__ Z) {
  int w = threadIdx.x >> 6, lane = threadIdx.x & 63;
  int m0 = blockIdx.y * 64 + (w >> 1) * 32;
  int n0 = blockIdx.x * 64 + (w & 1) * 32;
  f32x4 acc[2][2] = {};
  mm512(xt, E, attW, E + H, m0, n0, lane, acc);
  mm512(hb, H, attW + E, E + H, m0, n0, lane, acc);
  int fr = lane & 15, fq = lane >> 4;
  float zl[2][4] = {};
  #pragma unroll
  for (int mi = 0; mi < 2; mi++)
    #pragma unroll
    for (int ni = 0; ni < 2; ni++)
      #pragma unroll
      for (int j = 0; j < 4; j++) {
        int row = m0 + mi * 16 + fq * 4 + j;
        int col = n0 + ni * 16 + fr;
        float p = __expf(acc[mi][ni][j] + attb[col]);
        zl[mi][j] += p;
        pbuf[row * A + col] = __float2bfloat16(p * cnn[row * A + col]);
      }
  #pragma unroll
  for (int mi = 0; mi < 2; mi++)
    #pragma unroll
    for (int j = 0; j < 4; j++) {
      float v = zl[mi][j];
      v += __shfl_xor(v, 1); v += __shfl_xor(v, 2);
      v += __shfl_xor(v, 4); v += __shfl_xor(v, 8);
      if (fr == 0) atomicAdd(&Z[m0 + mi * 16 + fq * 4 + j], v);
    }
}

// x2 = [x_t | P'/Z] @ attd_W^T + attd_b   (bf16 out)
__global__ __launch_bounds__(256) void kx2(const bf16* __restrict__ xt,
                                           const bf16* __restrict__ pb,
                                           const bf16* __restrict__ attdW,
                                           const float* __restrict__ attdb,
                                           const float* __restrict__ Z,
                                           bf16* __restrict__ x2b) {
  int w = threadIdx.x >> 6, lane = threadIdx.x & 63;
  int m0 = blockIdx.y * 64 + (w >> 1) * 32;
  int n0 = blockIdx.x * 64 + (w & 1) * 32;
  f32x4 acc1[2][2] = {}, acc2[2][2] = {};
  mm512(xt, E, attdW, E + A, m0, n0, lane, acc1);
  mm512(pb, A, attdW + E, E + A, m0, n0, lane, acc2);
  int fr = lane & 15, fq = lane >> 4;
  #pragma unroll
  for (int mi = 0; mi < 2; mi++)
    #pragma unroll
    for (int ni = 0; ni < 2; ni++)
      #pragma unroll
      for (int j = 0; j < 4; j++) {
        int row = m0 + mi * 16 + fq * 4 + j;
        int col = n0 + ni * 16 + fr;
        float v = acc1[mi][ni][j] + acc2[mi][ni][j] / Z[row] + attdb[col];
        x2b[row * E + col] = __float2bfloat16(v);
      }
}

// gates = [x2 | h] @ [W_ih | W_hh]^T + bg ; fused LSTM cell update + masked writes.
// grid (16 j-tiles, 4 b-tiles); wave w computes gate-quarter w for the same 32x32 tile.
__global__ __launch_bounds__(256) void kgates(const bf16* __restrict__ xg,
                                              const bf16* __restrict__ hb,
                                              const bf16* __restrict__ Wih,
                                              const bf16* __restrict__ Whh,
                                              const float* __restrict__ bg,
                                              float* __restrict__ c,
                                              const int* __restrict__ len, int t,
                                              bf16* __restrict__ hOut,
                                              bf16* __restrict__ hid) {
  __shared__ float g[4][32][33];
  int w = threadIdx.x >> 6, lane = threadIdx.x & 63;
  int m0 = blockIdx.y * 32;
  int n0 = w * H + blockIdx.x * 32;
  f32x4 acc[2][2] = {};
  mm512(xg, E, Wih, E, m0, n0, lane, acc);
  mm512(hb, H, Whh, H, m0, n0, lane, acc);
  int fr = lane & 15, fq = lane >> 4;
  #pragma unroll
  for (int mi = 0; mi < 2; mi++)
    #pragma unroll
    for (int ni = 0; ni < 2; ni++)
      #pragma unroll
      for (int j = 0; j < 4; j++) {
        int bl = mi * 16 + fq * 4 + j;
        int jl = ni * 16 + fr;
        g[w][bl][jl] = acc[mi][ni][j] + bg[n0 + jl];
      }
  __syncthreads();
  int jl = threadIdx.x & 31;
  int jg = blockIdx.x * 32 + jl;
  #pragma unroll
  for (int it = 0; it < 4; it++) {
    int bl = (threadIdx.x >> 5) + it * 8;
    int b = m0 + bl;
    float gi = sigm(g[0][bl][jl]);
    float gf = sigm(g[1][bl][jl]);
    float gg = tanhf(g[2][bl][jl]);
    float go = sigm(g[3][bl][jl]);
    float cold = c[b * H + jg];
    float c2 = gf * cold + gi * gg;
    float h2 = go * tanhf(c2);
    bool act = t < len[b];
    c[b * H + jg] = act ? c2 : cold;
    hOut[b * H + jg] = act ? __float2bfloat16(h2) : hb[b * H + jg];
    hid[((size_t)t * B + b) * H + jg] = act ? __float2bfloat16(h2) : __float2bfloat16(0.f);
  }
}

// logits = hidden @ out_W^T + out_b, masked by (t < len[b]); 128x128 block tile.
__global__ __launch_bounds__(256) void kfinal(const bf16* __restrict__ hid,
                                              const bf16* __restrict__ Wo,
                                              const float* __restrict__ outb,
                                              const int* __restrict__ len,
                                              float* __restrict__ out) {
  int w = threadIdx.x >> 6, lane = threadIdx.x & 63;
  int m0 = blockIdx.y * 128 + (w >> 1) * 64;
  int n0 = blockIdx.x * 128 + (w & 1) * 64;
  int r = lane & 15, ko = (lane >> 4) << 3;
  f32x4 acc[4][4] = {};
  const bf16* pa = hid + (size_t)(m0 + r) * H + ko;
  const bf16* pb = Wo + (size_t)(n0 + r) * H + ko;
  #pragma unroll 2
  for (int k = 0; k < H; k += 32) {
    bf16x8s a[4], b[4];
    #pragma unroll
    for (int i = 0; i < 4; i++) {
      a[i] = ld8(pa + (size_t)i * 16 * H + k);
      b[i] = ld8(pb + (size_t)i * 16 * H + k);
    }
    #pragma unroll
    for (int mi = 0; mi < 4; mi++)
      #pragma unroll
      for (int ni = 0; ni < 4; ni++)
        acc[mi][ni] = __builtin_amdgcn_mfma_f32_16x16x32_bf16(a[mi], b[ni], acc[mi][ni], 0, 0, 0);
  }
  int fr = lane & 15, fq = lane >> 4;
  #pragma unroll
  for (int mi = 0; mi < 4; mi++)
    #pragma unroll
    for (int ni = 0; ni < 4; ni++)
      #pragma unroll
      for (int j = 0; j < 4; j++) {
        int row = m0 + mi * 16 + fq * 4 + j;
        int col = n0 + ni * 16 + fr;
        if (col < V) {
          int tt = row >> 7, bb = row & 127;
          float v = (tt < len[bb]) ? acc[mi][ni][j] + outb[col] : 0.f;
          out[(size_t)row * V + col] = v;
        }
      }
}

// ---------------- launch ----------------

extern "C" void kernel_launch(void* const* d_in, const int* in_sizes, int n_in,
                              void* d_out, int out_size, void* d_ws, size_t ws_size,
                              hipStream_t stream) {
  const float* feat   = (const float*)d_in[0];
  const int*   cap    = (const int*)d_in[1];
  const int*   len    = (const int*)d_in[2];
  const float* cnn    = (const float*)d_in[3];
  const float* embW   = (const float*)d_in[4];
  const float* Wih_f  = (const float*)d_in[5];
  const float* Whh_f  = (const float*)d_in[6];
  const float* bih    = (const float*)d_in[7];
  const float* bhh    = (const float*)d_in[8];
  const float* attW_f = (const float*)d_in[9];
  const float* attb   = (const float*)d_in[10];
  const float* attdW_f= (const float*)d_in[11];
  const float* attdb  = (const float*)d_in[12];
  const float* outW_f = (const float*)d_in[13];
  const float* outb   = (const float*)d_in[14];
  float* out = (float*)d_out;
  char* ws = (char*)d_ws;

  bf16*  xs    = (bf16*)(ws + 0);            // 8,388,608
  bf16*  attW  = (bf16*)(ws + 8388608);      // 1,048,576
  bf16*  attdW = (bf16*)(ws + 9437184);      // 1,048,576
  bf16*  Wih   = (bf16*)(ws + 10485760);     // 2,097,152
  bf16*  Whh   = (bf16*)(ws + 12582912);     // 2,097,152
  bf16*  outW  = (bf16*)(ws + 14680064);     // 10,354,688
  bf16*  hid   = (bf16*)(ws + 25034752);     // 8,388,608
  float* bg    = (float*)(ws + 33423360);    // 8,192
  bf16*  hbf0  = (bf16*)(ws + 33431552);     // 131,072
  bf16*  hbf1  = (bf16*)(ws + 33562624);     // 131,072
  float* cst   = (float*)(ws + 33693696);    // 262,144
  bf16*  pbuf  = (bf16*)(ws + 33955840);     // 131,072
  bf16*  x2b   = (bf16*)(ws + 34086912);     // 131,072
  float* Zb    = (float*)(ws + 34217984);    // 32,768

  kxs<<<4096, 256, 0, stream>>>(feat, cap, embW, xs);
  kcast<<<512, 256, 0, stream>>>(attW_f, attW, 131072);
  kcast<<<512, 256, 0, stream>>>(attdW_f, attdW, 131072);
  kcast<<<1024, 256, 0, stream>>>(Wih_f, Wih, 262144);
  kcast<<<1024, 256, 0, stream>>>(Whh_f, Whh, 262144);
  kpadW<<<5056, 256, 0, stream>>>(outW_f, outW);
  kbg<<<8, 256, 0, stream>>>(bih, bhh, bg);
  hipMemsetAsync(hbf0, 0, 131072, stream);
  hipMemsetAsync(cst, 0, 262144, stream);
  hipMemsetAsync(Zb, 0, 32768, stream);

  for (int t = 0; t < T; ++t) {
    bf16* hIn  = (t & 1) ? hbf1 : hbf0;
    bf16* hOut = (t & 1) ? hbf0 : hbf1;
    const bf16* xt = xs + (size_t)t * B * E;
    if (t) {
      kscore<<<dim3(8, 2), 256, 0, stream>>>(xt, hIn, attW, attb, cnn, pbuf, Zb + t * B);
      kx2<<<dim3(8, 2), 256, 0, stream>>>(xt, pbuf, attdW, attdb, Zb + t * B, x2b);
    }
    kgates<<<dim3(16, 4), 256, 0, stream>>>(t ? (const bf16*)x2b : xt, hIn, Wih, Whh,
                                            bg, cst, len, t, hOut, hid);
  }
  kfinal<<<dim3(79, 64), 256, 0, stream>>>(hid, outW, outb, len, out);
}